// Round 1
// baseline (336.768 us; speedup 1.0000x reference)
//
#include <hip/hip_runtime.h>
#include <cstdint>

#define HW 200704      // 448*448
#define IMG_W 448
#define NCLS 20
#define NDIM 256
#define NCHUNK 8
#define CHUNK 25088    // HW/8
#define CAP 3072       // candidate buffer (expect ~1250 at T=0.95)
#define LK 257         // padded LDS stride (257 mod 32 == 1 -> conflict-free)

// ---------------------------------------------------------------------------
// K0: transpose fmap [B,256,784] -> fmapT [B,784,256]
__global__ __launch_bounds__(256) void k_transpose(const float* __restrict__ fmap,
                                                   float* __restrict__ fmapT) {
  int g = blockIdx.x * 256 + threadIdx.x;   // 401408 total
  int d = g & 255;
  int s = (g >> 8) % 784;
  int b = g / 200704;
  fmapT[g] = fmap[(b * 256 + d) * 784 + s];
}

// ---------------------------------------------------------------------------
// K1: pseudo labels + bilinear weight scatter.
// Block = 16 rows x 64 cols tile; 2*28*7 = 392 blocks; each thread 4 pixels.
__global__ __launch_bounds__(256) void k_pseudo(const float* __restrict__ cam,
                                                const float* __restrict__ cls_label,
                                                const float* __restrict__ hig_p,
                                                const float* __restrict__ low_p,
                                                const float* __restrict__ bg_p,
                                                float* __restrict__ W,
                                                int* __restrict__ counts) {
  int blk = blockIdx.x;
  int b = blk / 196;
  int t = blk % 196;
  int tileY = t / 7, tileX = t % 7;
  __shared__ float lab[NCLS];
  if (threadIdx.x < NCLS) lab[threadIdx.x] = cls_label[b * NCLS + threadIdx.x];
  __syncthreads();
  float hig = hig_p[0], low = low_p[0], bg = bg_p[0];
  int tx = threadIdx.x & 63;
  int ty = threadIdx.x >> 6;
  int x = tileX * 64 + tx;
  const float* camb = cam + (size_t)b * NCLS * HW;
  for (int k = 0; k < 4; ++k) {
    int y = tileY * 16 + ty + k * 4;
    int pix = y * IMG_W + x;
    float top1 = -1.0f, second = -1.0f;
    int idx1 = 0;
#pragma unroll
    for (int c = 0; c < NCLS; ++c) {
      float v = camb[c * HW + pix] * lab[c];
      if (v > top1) { second = top1; top1 = v; idx1 = c; }
      else if (v > second) second = v;
    }
    // sequential where() chain, exactly as reference
    int ps = idx1 + 1;
    if (top1 < hig) ps = 255;
    if (top1 < low) ps = 0;
    if (top1 < bg)  ps = 0;
    if ((top1 - second < 0.3f) && (top1 > hig)) ps = 255;
    if (ps >= 1 && ps <= NCLS) {
      int cls = ps - 1;
      // bilinear (half-pixel, clamp) weights onto 28x28 source grid
      float sy = (y + 0.5f) * 0.0625f - 0.5f; sy = fminf(fmaxf(sy, 0.0f), 27.0f);
      float sx = (x + 0.5f) * 0.0625f - 0.5f; sx = fminf(fmaxf(sx, 0.0f), 27.0f);
      int fy0 = (int)sy, fx0 = (int)sx;
      int fy1 = min(fy0 + 1, 27), fx1 = min(fx0 + 1, 27);
      float wy = sy - (float)fy0, wx = sx - (float)fx0;
      float* Wb = W + (size_t)(b * NCLS + cls) * 784;
      atomicAdd(&Wb[fy0 * 28 + fx0], (1.0f - wy) * (1.0f - wx));
      atomicAdd(&Wb[fy0 * 28 + fx1], (1.0f - wy) * wx);
      atomicAdd(&Wb[fy1 * 28 + fx0], wy * (1.0f - wx));
      atomicAdd(&Wb[fy1 * 28 + fx1], wy * wx);
      atomicAdd(&counts[b * NCLS + cls], 1);
    }
  }
}

// ---------------------------------------------------------------------------
// block-wide argmax of (value desc, index asc) pairs
__device__ __forceinline__ void block_argmax(float& bv, int& bi, float* rv, int* ri) {
  int tid = threadIdx.x;
  rv[tid] = bv; ri[tid] = bi;
  __syncthreads();
  for (int s = 128; s > 0; s >>= 1) {
    if (tid < s) {
      float ov = rv[tid + s]; int oi = ri[tid + s];
      if (ov > rv[tid] || (ov == rv[tid] && oi < ri[tid])) { rv[tid] = ov; ri[tid] = oi; }
    }
    __syncthreads();
  }
  bv = rv[0]; bi = ri[0];
  __syncthreads();
}

// ---------------------------------------------------------------------------
// K2: per (b,c,chunk) exact top-25 of valid_cam with JAX tie-break.
// grid = 40*8 blocks.
__global__ __launch_bounds__(256) void k_topk_chunks(const float* __restrict__ cam,
                                                     const float* __restrict__ cls_label,
                                                     float* __restrict__ candV,
                                                     int* __restrict__ candI) {
  __shared__ float cv[CAP]; __shared__ int ci[CAP];
  __shared__ int cnt;
  __shared__ float rv[256]; __shared__ int ri[256];
  int bc = blockIdx.x >> 3, chunk = blockIdx.x & 7;
  int b = bc / NCLS, c = bc % NCLS;
  int tid = threadIdx.x;
  float* outV = candV + blockIdx.x * 25;
  int*   outI = candI + blockIdx.x * 25;
  float lab = cls_label[b * NCLS + c];
  int base = chunk * CHUNK;
  if (lab == 0.0f) {
    // valid_cam identically 0 -> stable top_k = first 25 indices, value 0
    if (tid < 25) { outV[tid] = 0.0f; outI[tid] = base + tid; }
    return;
  }
  if (tid == 0) cnt = 0;
  __syncthreads();
  const float* camc = cam + (size_t)(b * NCLS + c) * HW;
  for (int k = 0; k < 98; ++k) {
    int i = base + k * 256 + tid;
    float v = camc[i] * lab;
    if (v >= 0.95f) {                 // cam ~ U[0,1): 25th of 25088 ~= 0.999
      int pos = atomicAdd(&cnt, 1);
      if (pos < CAP) { cv[pos] = v; ci[pos] = i; }
    }
  }
  __syncthreads();
  int n = cnt;
  float lastV = 3.0e38f; int lastI = -1;
  if (n >= 25 && n <= CAP) {
    for (int r = 0; r < 25; ++r) {
      float bv = -1.0e30f; int bi = 0x7fffffff;
      for (int p = tid; p < n; p += 256) {
        float v = cv[p]; int i = ci[p];
        if (((v < lastV) || (v == lastV && i > lastI)) &&
            ((v > bv) || (v == bv && i < bi))) { bv = v; bi = i; }
      }
      block_argmax(bv, bi, rv, ri);
      lastV = bv; lastI = bi;
      if (tid == 0) { outV[r] = bv; outI[r] = bi; }
    }
  } else {
    // exact fallback: tournament over the raw chunk (practically never taken)
    for (int r = 0; r < 25; ++r) {
      float bv = -1.0e30f; int bi = 0x7fffffff;
      for (int k = 0; k < 98; ++k) {
        int i = base + k * 256 + tid;
        float v = camc[i] * lab;
        if (((v < lastV) || (v == lastV && i > lastI)) &&
            ((v > bv) || (v == bv && i < bi))) { bv = v; bi = i; }
      }
      block_argmax(bv, bi, rv, ri);
      lastV = bv; lastI = bi;
      if (tid == 0) { outV[r] = bv; outI[r] = bi; }
    }
  }
}

// ---------------------------------------------------------------------------
// K3: per (b,c): merge chunk candidates -> global top-25; feat_mask + feat_topk -> fsm
// grid = 40 blocks, 256 threads = feature dims.
__global__ __launch_bounds__(256) void k_features(const float* __restrict__ fmapT,
                                                  const float* __restrict__ W,
                                                  const int* __restrict__ counts,
                                                  const float* __restrict__ candV,
                                                  const int* __restrict__ candI,
                                                  const float* __restrict__ cls_label,
                                                  float* __restrict__ fsm_g) {
  __shared__ float sW[784];
  __shared__ float rv[256]; __shared__ int ri[256];
  __shared__ int topIdx[25];
  int bc = blockIdx.x;
  int b = bc / NCLS;
  int tid = threadIdx.x;
  for (int s = tid; s < 784; s += 256) sW[s] = W[(size_t)bc * 784 + s];
  // merge: union of 8 exact chunk top-25s contains the global top-25
  float mv = -1.0e30f; int mi = 0x7fffffff;
  if (tid < 200) { mv = candV[bc * 200 + tid]; mi = candI[bc * 200 + tid]; }
  float lastV = 3.0e38f; int lastI = -1;
  for (int r = 0; r < 25; ++r) {
    bool elig = (mv < lastV) || (mv == lastV && mi > lastI);
    float bv = elig ? mv : -1.0e30f;
    int bi = elig ? mi : 0x7fffffff;
    block_argmax(bv, bi, rv, ri);
    lastV = bv; lastI = bi;
    if (tid == 0) topIdx[r] = bi;
    __syncthreads();
  }
  // feat_mask = (W . fmapT) / max(count,1)
  const float* fT = fmapT + (size_t)b * 784 * 256;
  float acc = 0.0f;
  for (int s = 0; s < 784; ++s) acc += sW[s] * fT[s * 256 + tid];
  int cnt = counts[bc];
  float fm = acc / fmaxf((float)cnt, 1.0f);
  // feat_topk = mean of 25 bilinear gathers
  float at = 0.0f;
  for (int r = 0; r < 25; ++r) {
    int p = topIdx[r];
    int y = p / IMG_W, x = p % IMG_W;
    float sy = (y + 0.5f) * 0.0625f - 0.5f; sy = fminf(fmaxf(sy, 0.0f), 27.0f);
    float sx = (x + 0.5f) * 0.0625f - 0.5f; sx = fminf(fmaxf(sx, 0.0f), 27.0f);
    int fy0 = (int)sy, fx0 = (int)sx;
    int fy1 = min(fy0 + 1, 27), fx1 = min(fx0 + 1, 27);
    float wy = sy - (float)fy0, wx = sx - (float)fx0;
    at += (1.0f - wy) * (1.0f - wx) * fT[(fy0 * 28 + fx0) * 256 + tid]
        + (1.0f - wy) * wx          * fT[(fy0 * 28 + fx1) * 256 + tid]
        + wy          * (1.0f - wx) * fT[(fy1 * 28 + fx0) * 256 + tid]
        + wy          * wx          * fT[(fy1 * 28 + fx1) * 256 + tid];
  }
  at *= (1.0f / 25.0f);
  float pres = (cls_label[bc] > 0.5f) ? 1.0f : 0.0f;
  fsm_g[(size_t)bc * 256 + tid] = ((cnt == 0) ? at : fm) * pres;
}

// ---------------------------------------------------------------------------
// K4: sequential loss over b with EMA memory bank. Single block, 256 threads = dims.
__global__ __launch_bounds__(256) void k_loss(const float* __restrict__ fsm_g,
                                              const float* __restrict__ cls_label,
                                              const float* __restrict__ proj_w,
                                              const float* __restrict__ fc_init,
                                              float* __restrict__ out) {
  __shared__ float sFsm[NCLS * LK];
  __shared__ float sFc[NCLS * LK];
  __shared__ float sPw[NCLS * LK];
  __shared__ float sMat[NCLS * NCLS];   // cos, then logits
  __shared__ float sRow[NCLS];
  __shared__ float sNormI[NCLS], sNormC[NCLS];
  __shared__ int   sQual[NCLS];
  __shared__ float sPres[2][NCLS];
  __shared__ float sScal[2];            // [0]=loss_ccf, [1]=loss_cls
  int tid = threadIdx.x;
  for (int r = 0; r < NCLS; ++r) {
    sFc[r * LK + tid] = fc_init[r * 256 + tid];
    sPw[r * LK + tid] = proj_w[r * 256 + tid];
  }
  if (tid < 40) sPres[tid / NCLS][tid % NCLS] = cls_label[tid];
  if (tid == 0) { sScal[0] = 0.0f; sScal[1] = 0.0f; }
  __syncthreads();

  for (int b = 0; b < 2; ++b) {
    for (int r = 0; r < NCLS; ++r) sFsm[r * LK + tid] = fsm_g[(b * NCLS + r) * 256 + tid];
    __syncthreads();
    // row norms (fsm_i and fc); zero rows -> norm floor 1e-12 -> normalized 0
    if (tid < NCLS) {
      float s = 0.0f, t2 = 0.0f;
      for (int d = 0; d < 256; ++d) {
        float a = sFsm[tid * LK + d]; s += a * a;
        float f = sFc[tid * LK + d];  t2 += f * f;
      }
      sNormI[tid] = fmaxf(sqrtf(s), 1e-12f);
      sNormC[tid] = fmaxf(sqrtf(t2), 1e-12f);
    }
    __syncthreads();
    // cos[i][j] = clip(|<fsm_i, fc_j>| / (Mi*Mj), 1e-5, 1-1e-5)
    for (int pi = tid; pi < 400; pi += 256) {
      int i = pi / NCLS, j = pi % NCLS;
      float acc = 0.0f;
      for (int d = 0; d < 256; ++d) acc += sFsm[i * LK + d] * sFc[j * LK + d];
      float c0 = fabsf(acc / (sNormI[i] * sNormC[j]));
      c0 = fminf(fmaxf(c0, 1e-5f), 1.0f - 1e-5f);
      sMat[pi] = c0;
    }
    __syncthreads();
    // loss_ccf row partials + off-diagonal max + qualify
    if (tid < NCLS) {
      float pres = (sPres[b][tid] > 0.5f) ? 1.0f : 0.0f;
      float rs = 0.0f;
      float om = -3.0e38f;
      for (int j = 0; j < NCLS; ++j) {
        float c0 = sMat[tid * NCLS + j];
        float ident = (j == tid) ? pres : 0.0f;
        rs += ident * logf(c0) + (1.0f - ident) * log1pf(-c0);
        if (j != tid) om = fmaxf(om, c0);
      }
      sRow[tid] = rs;
      sQual[tid] = (pres > 0.5f && om < 0.6f) ? 1 : 0;
    }
    __syncthreads();
    if (tid == 0) {
      float s = 0.0f;
      for (int r = 0; r < NCLS; ++r) s += sRow[r];
      sScal[0] -= s / 400.0f;
    }
    __syncthreads();
    // logits = fsm_i @ proj_w^T (reuses sMat)
    for (int pi = tid; pi < 400; pi += 256) {
      int i = pi / NCLS, j = pi % NCLS;
      float acc = 0.0f;
      for (int d = 0; d < 256; ++d) acc += sFsm[i * LK + d] * sPw[j * LK + d];
      sMat[pi] = acc;
    }
    __syncthreads();
    // per-class BCE(softmax, onehot) term
    if (tid < NCLS) {
      float m = -3.0e38f;
      for (int j = 0; j < NCLS; ++j) m = fmaxf(m, sMat[tid * NCLS + j]);
      float S = 0.0f;
      for (int j = 0; j < NCLS; ++j) S += expf(sMat[tid * NCLS + j] - m);
      float ts = 0.0f;
      for (int j = 0; j < NCLS; ++j) {
        float p = expf(sMat[tid * NCLS + j] - m) / S;
        if (j == tid) ts += fmaxf(logf(p), -100.0f);
        else          ts += fmaxf(log1pf(-p), -100.0f);
      }
      sRow[tid] = -ts / 20.0f;
    }
    __syncthreads();
    if (tid == 0) {
      float add = 0.0f; int n = 0;
      for (int r = 0; r < NCLS; ++r) if (sQual[r]) { add += sRow[r]; n++; }
      float lc = sScal[1] + add;
      if (n > 0) lc = lc / fmaxf((float)n, 1.0f);   // divides the ACCUMULATED loss (ref semantics)
      sScal[1] = lc;
    }
    __syncthreads();
    // EMA bank update for qualified classes
    for (int r = 0; r < NCLS; ++r)
      if (sQual[r]) sFc[r * LK + tid] = 0.95f * sFc[r * LK + tid] + 0.05f * sFsm[r * LK + tid];
    __syncthreads();
  }
  if (tid == 0) out[0] = sScal[0] + sScal[1];
}

// ---------------------------------------------------------------------------
extern "C" void kernel_launch(void* const* d_in, const int* in_sizes, int n_in,
                              void* d_out, int out_size, void* d_ws, size_t ws_size,
                              hipStream_t stream) {
  const float* fmap      = (const float*)d_in[0];   // [2,256,28,28]
  const float* cam       = (const float*)d_in[1];   // [2,20,448,448]
  const float* cls_label = (const float*)d_in[2];   // [2,20]
  const float* proj_w    = (const float*)d_in[3];   // [20,256]
  const float* fc_init   = (const float*)d_in[4];   // [20,256]
  const float* hig       = (const float*)d_in[5];
  const float* low       = (const float*)d_in[6];
  const float* bg        = (const float*)d_in[7];
  float* out = (float*)d_out;

  char* ws = (char*)d_ws;
  float* W      = (float*)(ws);                 // 31360 floats  (125440 B)
  int*   counts = (int*)  (ws + 125440);        // 40 ints       (160 B)
  float* candV  = (float*)(ws + 125600);        // 8000 floats   (32000 B)
  int*   candI  = (int*)  (ws + 157600);        // 8000 ints     (32000 B)
  float* fsm    = (float*)(ws + 189600);        // 10240 floats  (40960 B)
  float* fmapT  = (float*)(ws + 230560);        // 401408 floats (1.6 MB)

  hipMemsetAsync(ws, 0, 125600, stream);        // zero W + counts (ws is re-poisoned per call)
  k_transpose  <<<1568, 256, 0, stream>>>(fmap, fmapT);
  k_pseudo     <<< 392, 256, 0, stream>>>(cam, cls_label, hig, low, bg, W, counts);
  k_topk_chunks<<< 320, 256, 0, stream>>>(cam, cls_label, candV, candI);
  k_features   <<<  40, 256, 0, stream>>>(fmapT, W, counts, candV, candI, cls_label, fsm);
  k_loss       <<<   1, 256, 0, stream>>>(fsm, cls_label, proj_w, fc_init, out);
}